// Round 2
// baseline (5924.195 us; speedup 1.0000x reference)
//
#include <hip/hip_runtime.h>
#include <stdint.h>

#define N_B 32
#define T_S 2048
#define H_D 1024
#define HSLOT ((size_t)N_B * H_D)   // one parity slot: 32 x 1024 packets

// One 6-stage DPP f32 add-reduce step: x += dpp(x) on enabled rows.
template<int CTRL, int ROWMASK>
__device__ __forceinline__ float dpp_add(float x) {
    int t = __builtin_amdgcn_update_dpp(0, __builtin_bit_cast(int, x),
                                        CTRL, ROWMASK, 0xf, true);
    return x + __builtin_bit_cast(float, t);
}

// Spin until packet tag matches `want`. Relaxed atomic loads (sc1, coherent),
// with a periodic RMW (executes at coherence point) as livelock insurance.
__device__ __forceinline__ unsigned long long wait_pkt(unsigned long long* a,
                                                       unsigned want,
                                                       unsigned long long v) {
    int spins = 0;
    while ((unsigned)(v >> 32) != want) {
        if ((++spins & 63) == 0)
            v = __hip_atomic_fetch_or(a, 0ull, __ATOMIC_RELAXED, __HIP_MEMORY_SCOPE_AGENT);
        else
            v = __hip_atomic_load(a, __ATOMIC_RELAXED, __HIP_MEMORY_SCOPE_AGENT);
    }
    return v;
}

// Persistent RNN kernel.
// Grid: 256 blocks x 512 threads. Block -> (group g of 2 batches, col slice s of 64).
// W slice (1024x64 fp32) in registers: w[k][j] = W[(rc+64k)*H + s*64 + wv*8 + j]
// h exchange: 8B packets (tag<<32 | fp32 bits), DOUBLE-BUFFERED by step parity.
__global__ __launch_bounds__(512, 2) void rnn_persist(
    const int* __restrict__ xx, const float* __restrict__ embed,
    const float* __restrict__ W, const float* __restrict__ bh,
    float* __restrict__ out, unsigned long long* __restrict__ hbuf)
{
    __shared__ float h_lds[2048];      // 16 row-blocks: [k][h0:64 | h1:64]
    __shared__ float xh_lds[2][64];    // embed slice for current step
    __shared__ int   x_lds[2][T_S];    // token ids for this group's 2 batches

    const int tid = threadIdx.x;
    const int blk = blockIdx.x;
    // XCD-swizzle heuristic: group g's 16 blocks share blk%8
    const int g = ((blk & 7) << 1) | ((blk >> 3) & 1);  // 0..15
    const int s = blk >> 4;                             // 0..15
    const int n0 = g * 2;
    const int wv = tid >> 6;   // wave id = col chunk 0..7
    const int rc = tid & 63;   // lane = row-chunk
    const int c_base = s * 64 + wv * 8;

    for (int e = tid; e < 2 * T_S; e += 512) {
        int b = e >> 11, t0 = e & (T_S - 1);
        x_lds[b][t0] = xx[(size_t)(n0 + b) * T_S + t0];
    }
    for (int e = tid; e < 2048; e += 512) h_lds[e] = 0.0f;
    __syncthreads();

    // W slice into registers (read once from HBM, never again)
    float w[16][8];
#pragma unroll
    for (int k = 0; k < 16; ++k) {
        const float4* p = (const float4*)(W + (size_t)(rc + 64 * k) * H_D + c_base);
        float4 a = p[0]; float4 b4 = p[1];
        w[k][0] = a.x;  w[k][1] = a.y;  w[k][2] = a.z;  w[k][3] = a.w;
        w[k][4] = b4.x; w[k][5] = b4.y; w[k][6] = b4.z; w[k][7] = b4.w;
    }

    // lanes 48..63 of each wave own its 16 outputs (2 batches x 8 cols)
    const int o  = rc - 48;
    const int ob = (o >> 3) & 1, oj = o & 7;
    int my_n = 0, my_c = 0, xh_idx = 0; float my_bias = 0.0f;
    if (o >= 0) {
        my_c    = c_base + oj;
        my_n    = n0 + ob;
        my_bias = bh[my_c];
        xh_idx  = ob * 64 + (wv * 8 + oj);
    }

    // prefetch embed rows for t=1
    float r_xh = 0.0f;
    if (tid < 128) {
        int b = tid >> 6, c_off = tid & 63;
        r_xh = embed[(size_t)x_lds[b][0] * H_D + (s * 64 + c_off)];
    }

    for (int t = 1; t <= T_S; ++t) {
        if (tid < 128) {
            int b = tid >> 6, c_off = tid & 63;
            xh_lds[b][c_off] = r_xh;
            if (t < T_S)
                r_xh = embed[(size_t)x_lds[b][t] * H_D + (s * 64 + c_off)];
        }
        // stage h_{t-1} from parity slot (t-1)&1  (t=1: h_0 = 0 already in LDS)
        if (t >= 2) {
            const unsigned tag = (unsigned)(t - 1);
            unsigned long long* base = hbuf + ((size_t)((t - 1) & 1)) * HSLOT;
            unsigned long long* a0 = base + (size_t)n0 * H_D + tid;
            unsigned long long* a1 = a0 + 512;
            unsigned long long* a2 = base + (size_t)(n0 + 1) * H_D + tid;
            unsigned long long* a3 = a2 + 512;
            unsigned long long v0 = __hip_atomic_load(a0, __ATOMIC_RELAXED, __HIP_MEMORY_SCOPE_AGENT);
            unsigned long long v1 = __hip_atomic_load(a1, __ATOMIC_RELAXED, __HIP_MEMORY_SCOPE_AGENT);
            unsigned long long v2 = __hip_atomic_load(a2, __ATOMIC_RELAXED, __HIP_MEMORY_SCOPE_AGENT);
            unsigned long long v3 = __hip_atomic_load(a3, __ATOMIC_RELAXED, __HIP_MEMORY_SCOPE_AGENT);
            v0 = wait_pkt(a0, tag, v0);
            v1 = wait_pkt(a1, tag, v1);
            v2 = wait_pkt(a2, tag, v2);
            v3 = wait_pkt(a3, tag, v3);
            h_lds[wv * 128 + rc]            = __builtin_bit_cast(float, (unsigned)v0);
            h_lds[(8 + wv) * 128 + rc]      = __builtin_bit_cast(float, (unsigned)v1);
            h_lds[wv * 128 + 64 + rc]       = __builtin_bit_cast(float, (unsigned)v2);
            h_lds[(8 + wv) * 128 + 64 + rc] = __builtin_bit_cast(float, (unsigned)v3);
        }
        __syncthreads();

        // partial GEMV: 16 rows x 8 cols x 2 batches per thread, W from registers
        float acc0[8], acc1[8];
#pragma unroll
        for (int j = 0; j < 8; ++j) { acc0[j] = 0.0f; acc1[j] = 0.0f; }
#pragma unroll
        for (int k = 0; k < 16; ++k) {
            float h0 = h_lds[k * 128 + rc];
            float h1 = h_lds[k * 128 + 64 + rc];
#pragma unroll
            for (int j = 0; j < 8; ++j) {
                acc0[j] = fmaf(h0, w[k][j], acc0[j]);
                acc1[j] = fmaf(h1, w[k][j], acc1[j]);
            }
        }

        // 64-lane reduce of 16 values; totals land in lanes 48..63 (row 3)
        float outv = 0.0f;
#pragma unroll
        for (int oo = 0; oo < 16; ++oo) {
            float v = (oo < 8) ? acc0[oo & 7] : acc1[oo & 7];
            v = dpp_add<0xB1,  0xf>(v);   // quad_perm xor1
            v = dpp_add<0x4E,  0xf>(v);   // quad_perm xor2
            v = dpp_add<0x141, 0xf>(v);   // row_half_mirror -> sum of 8
            v = dpp_add<0x140, 0xf>(v);   // row_mirror      -> sum of 16
            v = dpp_add<0x142, 0xa>(v);   // row_bcast15 -> rows 1,3
            v = dpp_add<0x143, 0xc>(v);   // row_bcast31 -> row 3 = total
            if (o == oo) outv = v;
        }

        if (o >= 0) {
            float pre = outv + ((const float*)xh_lds)[xh_idx] + my_bias;
            float hv  = tanhf(pre);
            out[((size_t)my_n * T_S + (t - 1)) * H_D + my_c] = hv;
            if (t == T_S)
                out[(size_t)N_B * T_S * H_D + (size_t)my_n * H_D + my_c] = hv;
            // publish into parity slot t&1
            unsigned long long p = ((unsigned long long)(unsigned)t << 32)
                                 | (unsigned long long)__builtin_bit_cast(unsigned, hv);
            __hip_atomic_store(hbuf + ((size_t)(t & 1)) * HSLOT + (size_t)my_n * H_D + my_c,
                               p, __ATOMIC_RELAXED, __HIP_MEMORY_SCOPE_AGENT);
        }
        __syncthreads();
    }
}

extern "C" void kernel_launch(void* const* d_in, const int* in_sizes, int n_in,
                              void* d_out, int out_size, void* d_ws, size_t ws_size,
                              hipStream_t stream) {
    const int*   xx    = (const int*)d_in[0];
    const float* embed = (const float*)d_in[1];
    const float* W     = (const float*)d_in[2];
    const float* bh    = (const float*)d_in[3];
    float* out = (float*)d_out;
    unsigned long long* hbuf = (unsigned long long*)d_ws;

    // clear tags in BOTH parity slots each call (kills cross-replay stale-tag match)
    hipMemsetAsync(d_ws, 0, 2 * HSLOT * sizeof(unsigned long long), stream);

    void* args[] = { (void*)&xx, (void*)&embed, (void*)&W, (void*)&bh,
                     (void*)&out, (void*)&hbuf };
    hipLaunchCooperativeKernel((const void*)rnn_persist, dim3(256), dim3(512),
                               args, 0, stream);
}

// Round 3
// 5850.708 us; speedup vs baseline: 1.0126x; 1.0126x over previous
//
#include <hip/hip_runtime.h>
#include <stdint.h>

#define N_B 32
#define T_S 2048
#define H_D 1024
#define HSLOT ((size_t)N_B * H_D)   // one parity slot: 32 x 1024 packets

// One 6-stage DPP f32 add-reduce step: x += dpp(x) on enabled rows.
template<int CTRL, int ROWMASK>
__device__ __forceinline__ float dpp_add(float x) {
    int t = __builtin_amdgcn_update_dpp(0, __builtin_bit_cast(int, x),
                                        CTRL, ROWMASK, 0xf, true);
    return x + __builtin_bit_cast(float, t);
}

// Spin until packet tag matches `want`. Relaxed atomic loads, with a periodic
// RMW (executes at the coherence point) as livelock insurance.
__device__ __forceinline__ unsigned long long wait_pkt(unsigned long long* a,
                                                       unsigned want,
                                                       unsigned long long v) {
    int spins = 0;
    while ((unsigned)(v >> 32) != want) {
        if ((++spins & 63) == 0)
            v = __hip_atomic_fetch_or(a, 0ull, __ATOMIC_RELAXED, __HIP_MEMORY_SCOPE_AGENT);
        else
            v = __hip_atomic_load(a, __ATOMIC_RELAXED, __HIP_MEMORY_SCOPE_AGENT);
    }
    return v;
}

// Force the 128 W values to stay register-resident across the t-loop:
// "+v" makes each value an input AND output of a 0-instruction asm, so the
// compiler cannot rematerialize them from memory inside the loop.
#define PIN_ROW(K) asm volatile("" \
    : "+v"(w[K][0]), "+v"(w[K][1]), "+v"(w[K][2]), "+v"(w[K][3]), \
      "+v"(w[K][4]), "+v"(w[K][5]), "+v"(w[K][6]), "+v"(w[K][7]))

// Persistent RNN kernel.
// Grid: 256 blocks x 512 threads. Block -> (group g of 2 batches, col slice s of 64).
// W slice (1024x64 fp32) in registers: w[k][j] = W[(rc+64k)*H + s*64 + wv*8 + j]
// h exchange: 8B packets (tag<<32 | fp32 bits), double-buffered by step parity.
__global__ __launch_bounds__(512, 2) void rnn_persist(
    const int* __restrict__ xx, const float* __restrict__ embed,
    const float* __restrict__ W, const float* __restrict__ bh,
    float* __restrict__ out, unsigned long long* __restrict__ hbuf)
{
    __shared__ __align__(8) float h_pair[1024][2];  // [row][batch0,batch1]
    __shared__ float xh_lds[2][64];                 // embed slice, current step
    __shared__ int   x_lds[2][T_S];                 // token ids, this group's 2 batches

    const int tid = threadIdx.x;
    const int blk = blockIdx.x;
    // XCD-swizzle heuristic: group g's 16 blocks share blk%8 (same XCD if round-robin)
    const int g = ((blk & 7) << 1) | ((blk >> 3) & 1);  // 0..15
    const int s = blk >> 4;                             // 0..15
    const int n0 = g * 2;
    const int wv = tid >> 6;   // wave id = col chunk 0..7
    const int rc = tid & 63;   // lane = row-chunk
    const int c_base = s * 64 + wv * 8;

    for (int e = tid; e < 2 * T_S; e += 512) {
        int b = e >> 11, t0 = e & (T_S - 1);
        x_lds[b][t0] = xx[(size_t)(n0 + b) * T_S + t0];
    }
    for (int e = tid; e < 1024; e += 512) {
        h_pair[e][0] = 0.0f; h_pair[e][1] = 0.0f;
    }
    __syncthreads();

    // W slice into registers (read once from HBM, never again)
    float w[16][8];
#pragma unroll
    for (int k = 0; k < 16; ++k) {
        const float4* p = (const float4*)(W + (size_t)(rc + 64 * k) * H_D + c_base);
        float4 a = p[0]; float4 b4 = p[1];
        w[k][0] = a.x;  w[k][1] = a.y;  w[k][2] = a.z;  w[k][3] = a.w;
        w[k][4] = b4.x; w[k][5] = b4.y; w[k][6] = b4.z; w[k][7] = b4.w;
    }

    // lanes 48..63 of each wave own its 16 outputs (2 batches x 8 cols)
    const int o  = rc - 48;
    const int ob = (o >> 3) & 1, oj = o & 7;
    int my_n = 0, my_c = 0, xh_idx = 0; float my_bias = 0.0f;
    if (o >= 0) {
        my_c    = c_base + oj;
        my_n    = n0 + ob;
        my_bias = bh[my_c];
        xh_idx  = ob * 64 + (wv * 8 + oj);
    }

    // prefetch embed rows for t=1
    float r_xh = 0.0f;
    if (tid < 128) {
        int b = tid >> 6, c_off = tid & 63;
        r_xh = embed[(size_t)x_lds[b][0] * H_D + (s * 64 + c_off)];
    }

    for (int t = 1; t <= T_S; ++t) {
        if (tid < 128) {
            int b = tid >> 6, c_off = tid & 63;
            xh_lds[b][c_off] = r_xh;
            if (t < T_S)
                r_xh = embed[(size_t)x_lds[b][t] * H_D + (s * 64 + c_off)];
        }
        // stage h_{t-1} from parity slot (t-1)&1  (t=1: h_0 = 0 already in LDS)
        if (t >= 2) {
            const unsigned tag = (unsigned)(t - 1);
            unsigned long long* base = hbuf + ((size_t)((t - 1) & 1)) * HSLOT;
            unsigned long long* a0 = base + (size_t)n0 * H_D + tid;
            unsigned long long* a1 = a0 + 512;
            unsigned long long* a2 = base + (size_t)(n0 + 1) * H_D + tid;
            unsigned long long* a3 = a2 + 512;
            unsigned long long v0 = __hip_atomic_load(a0, __ATOMIC_RELAXED, __HIP_MEMORY_SCOPE_AGENT);
            unsigned long long v1 = __hip_atomic_load(a1, __ATOMIC_RELAXED, __HIP_MEMORY_SCOPE_AGENT);
            unsigned long long v2 = __hip_atomic_load(a2, __ATOMIC_RELAXED, __HIP_MEMORY_SCOPE_AGENT);
            unsigned long long v3 = __hip_atomic_load(a3, __ATOMIC_RELAXED, __HIP_MEMORY_SCOPE_AGENT);
            v0 = wait_pkt(a0, tag, v0);
            v1 = wait_pkt(a1, tag, v1);
            v2 = wait_pkt(a2, tag, v2);
            v3 = wait_pkt(a3, tag, v3);
            float2 p0 = { __builtin_bit_cast(float, (unsigned)v0),
                          __builtin_bit_cast(float, (unsigned)v2) };
            float2 p1 = { __builtin_bit_cast(float, (unsigned)v1),
                          __builtin_bit_cast(float, (unsigned)v3) };
            ((float2*)h_pair)[tid]       = p0;   // row tid
            ((float2*)h_pair)[tid + 512] = p1;   // row tid+512
        }
        __syncthreads();

        // keep W register-resident (0-instruction asm, defeats remat)
        PIN_ROW(0);  PIN_ROW(1);  PIN_ROW(2);  PIN_ROW(3);
        PIN_ROW(4);  PIN_ROW(5);  PIN_ROW(6);  PIN_ROW(7);
        PIN_ROW(8);  PIN_ROW(9);  PIN_ROW(10); PIN_ROW(11);
        PIN_ROW(12); PIN_ROW(13); PIN_ROW(14); PIN_ROW(15);

        // partial GEMV: 16 rows x 8 cols x 2 batches per thread, W from registers
        float acc0[8], acc1[8];
#pragma unroll
        for (int j = 0; j < 8; ++j) { acc0[j] = 0.0f; acc1[j] = 0.0f; }
        const float2* hp = (const float2*)h_pair;
#pragma unroll
        for (int k = 0; k < 16; ++k) {
            float2 h01 = hp[k * 64 + rc];
#pragma unroll
            for (int j = 0; j < 8; ++j) {
                acc0[j] = fmaf(h01.x, w[k][j], acc0[j]);
                acc1[j] = fmaf(h01.y, w[k][j], acc1[j]);
            }
        }

        // 64-lane reduce of 16 values; totals land in lanes 48..63 (row 3)
        float outv = 0.0f;
#pragma unroll
        for (int oo = 0; oo < 16; ++oo) {
            float v = (oo < 8) ? acc0[oo & 7] : acc1[oo & 7];
            v = dpp_add<0xB1,  0xf>(v);   // quad_perm xor1
            v = dpp_add<0x4E,  0xf>(v);   // quad_perm xor2
            v = dpp_add<0x141, 0xf>(v);   // row_half_mirror -> sum of 8
            v = dpp_add<0x140, 0xf>(v);   // row_mirror      -> sum of 16
            v = dpp_add<0x142, 0xa>(v);   // row_bcast15 -> rows 1,3
            v = dpp_add<0x143, 0xc>(v);   // row_bcast31 -> row 3 = total
            if (o == oo) outv = v;
        }

        if (o >= 0) {
            float pre = outv + ((const float*)xh_lds)[xh_idx] + my_bias;
            float hv  = tanhf(pre);
            // publish FIRST (consumer-visible store leads the critical path)
            unsigned long long p = ((unsigned long long)(unsigned)t << 32)
                                 | (unsigned long long)__builtin_bit_cast(unsigned, hv);
            __hip_atomic_store(hbuf + ((size_t)(t & 1)) * HSLOT + (size_t)my_n * H_D + my_c,
                               p, __ATOMIC_RELAXED, __HIP_MEMORY_SCOPE_AGENT);
            out[((size_t)my_n * T_S + (t - 1)) * H_D + my_c] = hv;
            if (t == T_S)
                out[(size_t)N_B * T_S * H_D + (size_t)my_n * H_D + my_c] = hv;
        }
        __syncthreads();
    }
}

extern "C" void kernel_launch(void* const* d_in, const int* in_sizes, int n_in,
                              void* d_out, int out_size, void* d_ws, size_t ws_size,
                              hipStream_t stream) {
    const int*   xx    = (const int*)d_in[0];
    const float* embed = (const float*)d_in[1];
    const float* W     = (const float*)d_in[2];
    const float* bh    = (const float*)d_in[3];
    float* out = (float*)d_out;
    unsigned long long* hbuf = (unsigned long long*)d_ws;

    // clear tags in BOTH parity slots each call (kills cross-replay stale-tag match)
    hipMemsetAsync(d_ws, 0, 2 * HSLOT * sizeof(unsigned long long), stream);

    void* args[] = { (void*)&xx, (void*)&embed, (void*)&W, (void*)&bh,
                     (void*)&out, (void*)&hbuf };
    hipLaunchCooperativeKernel((const void*)rnn_persist, dim3(256), dim3(512),
                               args, 0, stream);
}

// Round 4
// 5830.133 us; speedup vs baseline: 1.0161x; 1.0035x over previous
//
#include <hip/hip_runtime.h>
#include <stdint.h>

#define N_B 32
#define T_S 2048
#define H_D 1024
#define HSLOT ((size_t)N_B * H_D)   // one parity slot: 32 x 1024 packets

// One 6-stage DPP f32 add-reduce step: x += dpp(x) on enabled rows.
template<int CTRL, int ROWMASK>
__device__ __forceinline__ float dpp_add(float x) {
    int t = __builtin_amdgcn_update_dpp(0, __builtin_bit_cast(int, x),
                                        CTRL, ROWMASK, 0xf, true);
    return x + __builtin_bit_cast(float, t);
}

// Spin until packet tag matches `want`. Relaxed atomic loads, with a periodic
// RMW (executes at the coherence point) as livelock insurance.
__device__ __forceinline__ unsigned long long wait_pkt(unsigned long long* a,
                                                       unsigned want,
                                                       unsigned long long v) {
    int spins = 0;
    while ((unsigned)(v >> 32) != want) {
        if ((++spins & 63) == 0)
            v = __hip_atomic_fetch_or(a, 0ull, __ATOMIC_RELAXED, __HIP_MEMORY_SCOPE_AGENT);
        else
            v = __hip_atomic_load(a, __ATOMIC_RELAXED, __HIP_MEMORY_SCOPE_AGENT);
    }
    return v;
}

// Keep W values materialized in VGPRs at this point (remat barrier).
#define PIN_ROW(K) asm volatile("" \
    : "+v"(w[K][0]), "+v"(w[K][1]), "+v"(w[K][2]), "+v"(w[K][3]), \
      "+v"(w[K][4]), "+v"(w[K][5]), "+v"(w[K][6]), "+v"(w[K][7]))

// fast tanh: clamp + v_exp_f32 + v_rcp_f32;  |err| ~1e-6, threshold is 1.3e-2
__device__ __forceinline__ float fast_tanh(float x) {
    float xc = fminf(fmaxf(x, -10.0f), 10.0f);
    float e  = __builtin_amdgcn_exp2f(xc * 2.885390081777927f);  // e^{2x}
    return (e - 1.0f) * __builtin_amdgcn_rcpf(e + 1.0f);
}

// Persistent RNN kernel.
// Grid: 256 blocks x 512 threads. Block -> (group g of 2 batches, col slice s of 64).
// W slice (1024x64 fp32) in registers: w[k][j] = W[(rc+64k)*H + s*64 + wv*8 + j]
// h exchange: 8B packets (tag<<32 | fp32 bits), double-buffered by step parity.
// waves_per_eu(2,2): pin occupancy target to 2 waves/EU -> 256-VGPR budget, so
// the allocator keeps the 128 W values live instead of rematerializing from L2.
__global__ void __attribute__((amdgpu_flat_work_group_size(512, 512),
                               amdgpu_waves_per_eu(2, 2)))
rnn_persist(
    const int* __restrict__ xx, const float* __restrict__ embed,
    const float* __restrict__ W, const float* __restrict__ bh,
    float* __restrict__ out, unsigned long long* __restrict__ hbuf)
{
    __shared__ __align__(8) float h_pair[1024][2];  // [row][batch0,batch1]
    __shared__ float xh_lds[2][64];                 // embed slice, current step
    __shared__ int   x_lds[2][T_S];                 // token ids, this group's 2 batches

    const int tid = threadIdx.x;
    const int blk = blockIdx.x;
    // XCD-swizzle heuristic: group g's 16 blocks share blk%8 (same XCD if round-robin)
    const int g = ((blk & 7) << 1) | ((blk >> 3) & 1);  // 0..15
    const int s = blk >> 4;                             // 0..15
    const int n0 = g * 2;
    const int wv = tid >> 6;   // wave id = col chunk 0..7
    const int rc = tid & 63;   // lane = row-chunk
    const int c_base = s * 64 + wv * 8;

    for (int e = tid; e < 2 * T_S; e += 512) {
        int b = e >> 11, t0 = e & (T_S - 1);
        x_lds[b][t0] = xx[(size_t)(n0 + b) * T_S + t0];
    }
    for (int e = tid; e < 1024; e += 512) {
        h_pair[e][0] = 0.0f; h_pair[e][1] = 0.0f;
    }
    __syncthreads();

    // W slice into registers (read once from HBM, never again)
    float w[16][8];
#pragma unroll
    for (int k = 0; k < 16; ++k) {
        const float4* p = (const float4*)(W + (size_t)(rc + 64 * k) * H_D + c_base);
        float4 a = p[0]; float4 b4 = p[1];
        w[k][0] = a.x;  w[k][1] = a.y;  w[k][2] = a.z;  w[k][3] = a.w;
        w[k][4] = b4.x; w[k][5] = b4.y; w[k][6] = b4.z; w[k][7] = b4.w;
    }

    // lanes 48..63 of each wave own its 16 outputs (2 batches x 8 cols)
    const int o  = rc - 48;
    const int ob = (o >> 3) & 1, oj = o & 7;
    int my_n = 0, my_c = 0, xh_idx = 0; float my_bias = 0.0f;
    if (o >= 0) {
        my_c    = c_base + oj;
        my_n    = n0 + ob;
        my_bias = bh[my_c];
        xh_idx  = ob * 64 + (wv * 8 + oj);
    }

    // prefetch embed rows for t=1
    float r_xh = 0.0f;
    if (tid < 128) {
        int b = tid >> 6, c_off = tid & 63;
        r_xh = embed[(size_t)x_lds[b][0] * H_D + (s * 64 + c_off)];
    }

    for (int t = 1; t <= T_S; ++t) {
        if (tid < 128) {
            int b = tid >> 6, c_off = tid & 63;
            xh_lds[b][c_off] = r_xh;
            if (t < T_S)
                r_xh = embed[(size_t)x_lds[b][t] * H_D + (s * 64 + c_off)];
        }
        // stage h_{t-1} from parity slot (t-1)&1  (t=1: h_0 = 0 already in LDS)
        if (t >= 2) {
            const unsigned tag = (unsigned)(t - 1);
            unsigned long long* base = hbuf + ((size_t)((t - 1) & 1)) * HSLOT;
            unsigned long long* a0 = base + (size_t)n0 * H_D + tid;
            unsigned long long* a1 = a0 + 512;
            unsigned long long* a2 = base + (size_t)(n0 + 1) * H_D + tid;
            unsigned long long* a3 = a2 + 512;
            unsigned long long v0 = __hip_atomic_load(a0, __ATOMIC_RELAXED, __HIP_MEMORY_SCOPE_AGENT);
            unsigned long long v1 = __hip_atomic_load(a1, __ATOMIC_RELAXED, __HIP_MEMORY_SCOPE_AGENT);
            unsigned long long v2 = __hip_atomic_load(a2, __ATOMIC_RELAXED, __HIP_MEMORY_SCOPE_AGENT);
            unsigned long long v3 = __hip_atomic_load(a3, __ATOMIC_RELAXED, __HIP_MEMORY_SCOPE_AGENT);
            v0 = wait_pkt(a0, tag, v0);
            v1 = wait_pkt(a1, tag, v1);
            v2 = wait_pkt(a2, tag, v2);
            v3 = wait_pkt(a3, tag, v3);
            float2 p0 = { __builtin_bit_cast(float, (unsigned)v0),
                          __builtin_bit_cast(float, (unsigned)v2) };
            float2 p1 = { __builtin_bit_cast(float, (unsigned)v1),
                          __builtin_bit_cast(float, (unsigned)v3) };
            ((float2*)h_pair)[tid]       = p0;   // row tid
            ((float2*)h_pair)[tid + 512] = p1;   // row tid+512
        }
        __syncthreads();

        // keep W register-resident
        PIN_ROW(0);  PIN_ROW(1);  PIN_ROW(2);  PIN_ROW(3);
        PIN_ROW(4);  PIN_ROW(5);  PIN_ROW(6);  PIN_ROW(7);
        PIN_ROW(8);  PIN_ROW(9);  PIN_ROW(10); PIN_ROW(11);
        PIN_ROW(12); PIN_ROW(13); PIN_ROW(14); PIN_ROW(15);

        // partial GEMV: 16 rows x 8 cols x 2 batches per thread, W from registers
        float acc0[8], acc1[8];
#pragma unroll
        for (int j = 0; j < 8; ++j) { acc0[j] = 0.0f; acc1[j] = 0.0f; }
        const float2* hp = (const float2*)h_pair;
#pragma unroll
        for (int k = 0; k < 16; ++k) {
            float2 h01 = hp[k * 64 + rc];
#pragma unroll
            for (int j = 0; j < 8; ++j) {
                acc0[j] = fmaf(h01.x, w[k][j], acc0[j]);
                acc1[j] = fmaf(h01.y, w[k][j], acc1[j]);
            }
        }

        // 64-lane reduce of 16 values; totals land in lanes 48..63 (row 3)
        float outv = 0.0f;
#pragma unroll
        for (int oo = 0; oo < 16; ++oo) {
            float v = (oo < 8) ? acc0[oo & 7] : acc1[oo & 7];
            v = dpp_add<0xB1,  0xf>(v);   // quad_perm xor1
            v = dpp_add<0x4E,  0xf>(v);   // quad_perm xor2
            v = dpp_add<0x141, 0xf>(v);   // row_half_mirror -> sum of 8
            v = dpp_add<0x140, 0xf>(v);   // row_mirror      -> sum of 16
            v = dpp_add<0x142, 0xa>(v);   // row_bcast15 -> rows 1,3
            v = dpp_add<0x143, 0xc>(v);   // row_bcast31 -> row 3 = total
            if (o == oo) outv = v;
        }

        if (o >= 0) {
            float pre = outv + ((const float*)xh_lds)[xh_idx] + my_bias;
            float hv  = fast_tanh(pre);
            // publish FIRST (consumer-visible store leads the critical path)
            unsigned long long p = ((unsigned long long)(unsigned)t << 32)
                                 | (unsigned long long)__builtin_bit_cast(unsigned, hv);
            __hip_atomic_store(hbuf + ((size_t)(t & 1)) * HSLOT + (size_t)my_n * H_D + my_c,
                               p, __ATOMIC_RELAXED, __HIP_MEMORY_SCOPE_AGENT);
            out[((size_t)my_n * T_S + (t - 1)) * H_D + my_c] = hv;
            if (t == T_S)
                out[(size_t)N_B * T_S * H_D + (size_t)my_n * H_D + my_c] = hv;
        }
        __syncthreads();
    }
}

extern "C" void kernel_launch(void* const* d_in, const int* in_sizes, int n_in,
                              void* d_out, int out_size, void* d_ws, size_t ws_size,
                              hipStream_t stream) {
    const int*   xx    = (const int*)d_in[0];
    const float* embed = (const float*)d_in[1];
    const float* W     = (const float*)d_in[2];
    const float* bh    = (const float*)d_in[3];
    float* out = (float*)d_out;
    unsigned long long* hbuf = (unsigned long long*)d_ws;

    // clear tags in BOTH parity slots each call (kills cross-replay stale-tag match)
    hipMemsetAsync(d_ws, 0, 2 * HSLOT * sizeof(unsigned long long), stream);

    void* args[] = { (void*)&xx, (void*)&embed, (void*)&W, (void*)&bh,
                     (void*)&out, (void*)&hbuf };
    hipLaunchCooperativeKernel((const void*)rnn_persist, dim3(256), dim3(512),
                               args, 0, stream);
}